// Round 1
// baseline (4894.983 us; speedup 1.0000x reference)
//
#include <hip/hip_runtime.h>

#define T_STEPS 256
#define BATCH   64
#define HID     1024
#define DIN     512
#define NCLS    1000

// ---------------------------------------------------------------------------
// Fused RNN step, both layers pipelined across blockIdx.z.
//   grid: (32 j-tiles, 4 b-groups, 2 layers), block: 1024 threads (16 waves)
//   Thread slot: ks = tid&31 (K-split, lane-contiguous for coalescing),
//                jg = (tid>>5)&7 (j-quad), bgs = tid>>8 (b-quad).
//   Each thread: acc[4j][4b] partials over its k-slice; k elements taken at
//   float4 granularity k = i*128 + ks*4 so that lanes 0..31 read a contiguous
//   512B segment per instruction. Partials reduced in-wave via 5-round
//   shfl_xor butterfly (lane bits 0..4 == ks). No LDS needed.
// ---------------------------------------------------------------------------
__device__ __forceinline__ void mm_seg(const float* __restrict__ A, long rsA,
                                       const float* __restrict__ W, int K,
                                       int jbase, int bbase, int ks,
                                       float acc[4][4]) {
    const int ni = K >> 7;  // K / 128
    for (int i = 0; i < ni; ++i) {
        const int k = (i << 7) + (ks << 2);
        float4 w[4], a[4];
#pragma unroll
        for (int jj = 0; jj < 4; ++jj)
            w[jj] = *(const float4*)(W + (size_t)(jbase + jj) * K + k);
#pragma unroll
        for (int bb = 0; bb < 4; ++bb)
            a[bb] = *(const float4*)(A + (size_t)(bbase + bb) * rsA + k);
#pragma unroll
        for (int jj = 0; jj < 4; ++jj)
#pragma unroll
            for (int bb = 0; bb < 4; ++bb) {
                acc[jj][bb] += w[jj].x * a[bb].x;
                acc[jj][bb] += w[jj].y * a[bb].y;
                acc[jj][bb] += w[jj].z * a[bb].z;
                acc[jj][bb] += w[jj].w * a[bb].w;
            }
    }
}

__global__ __launch_bounds__(1024)
void step_phase(int p,
                const float* __restrict__ x,
                const float* __restrict__ w_ih0, const float* __restrict__ w_hh0,
                const float* __restrict__ w_ih1, const float* __restrict__ w_hh1,
                float* __restrict__ h1pp, float* __restrict__ h2pp) {
    const int z   = blockIdx.z;
    const int jb  = blockIdx.x;   // 0..31  -> 32 j's each
    const int bg  = blockIdx.y;   // 0..3   -> 16 b's each
    const int tid = threadIdx.x;
    const int ks  = tid & 31;
    const int jg  = (tid >> 5) & 7;
    const int bgs = tid >> 8;
    const int jbase = jb * 32 + jg * 4;
    const int bbase = bg * 16 + bgs * 4;

    float acc[4][4] = {{0.f}};
    float* outp;

    if (z == 0) {
        // layer-1 step p: h1_{p+1} = relu(W_ih0 x_p + W_hh0 h1_p)
        if (p >= T_STEPS) return;
        mm_seg(x + (size_t)p * DIN, (long)T_STEPS * DIN, w_ih0, DIN,
               jbase, bbase, ks, acc);
        mm_seg(h1pp + (size_t)(p & 1) * BATCH * HID, HID, w_hh0, HID,
               jbase, bbase, ks, acc);
        outp = h1pp + (size_t)((p + 1) & 1) * BATCH * HID;
    } else {
        // layer-2 step q = p-1: h2_{q+1} = relu(W_ih1 h1_{q+1} + W_hh1 h2_q)
        if (p == 0) return;
        const int q = p - 1;
        mm_seg(h1pp + (size_t)(p & 1) * BATCH * HID, HID, w_ih1, HID,
               jbase, bbase, ks, acc);
        mm_seg(h2pp + (size_t)(q & 1) * BATCH * HID, HID, w_hh1, HID,
               jbase, bbase, ks, acc);
        outp = h2pp + (size_t)((q + 1) & 1) * BATCH * HID;
    }

    // in-wave butterfly over lane bits 0..4 (== ks): sums the 32 K-partials
#pragma unroll
    for (int m = 1; m <= 16; m <<= 1) {
#pragma unroll
        for (int jj = 0; jj < 4; ++jj)
#pragma unroll
            for (int bb = 0; bb < 4; ++bb)
                acc[jj][bb] += __shfl_xor(acc[jj][bb], m, 64);
    }

    if (ks == 0) {
#pragma unroll
        for (int bb = 0; bb < 4; ++bb) {
            float4 v;
            v.x = fmaxf(acc[0][bb], 0.f);
            v.y = fmaxf(acc[1][bb], 0.f);
            v.z = fmaxf(acc[2][bb], 0.f);
            v.w = fmaxf(acc[3][bb], 0.f);
            *(float4*)(outp + (size_t)(bbase + bb) * HID + jbase) = v;
        }
    }
}

__global__ void zero_kernel(float* __restrict__ p, int n) {
    int i = blockIdx.x * blockDim.x + threadIdx.x;
    if (i < n) p[i] = 0.f;
}

// out[b][c] = sum_k h2[b][k] * w_fc[c][k];  grid (64, 4) x 256
__global__ void fc_kernel(const float* __restrict__ h2,
                          const float* __restrict__ w_fc,
                          float* __restrict__ out) {
    __shared__ float hs[HID];
    const int b = blockIdx.x;
    for (int i = threadIdx.x; i < HID; i += 256) hs[i] = h2[(size_t)b * HID + i];
    __syncthreads();
    const int c = blockIdx.y * 256 + threadIdx.x;
    if (c < NCLS) {
        const float* w = w_fc + (size_t)c * HID;
        float s = 0.f;
        for (int k = 0; k < HID; k += 4) {
            float4 wv = *(const float4*)(w + k);
            s += wv.x * hs[k] + wv.y * hs[k + 1] + wv.z * hs[k + 2] + wv.w * hs[k + 3];
        }
        out[(size_t)b * NCLS + c] = s;
    }
}

extern "C" void kernel_launch(void* const* d_in, const int* in_sizes, int n_in,
                              void* d_out, int out_size, void* d_ws, size_t ws_size,
                              hipStream_t stream) {
    const float* x     = (const float*)d_in[0];
    const float* w_ih0 = (const float*)d_in[1];
    const float* w_hh0 = (const float*)d_in[2];
    const float* w_ih1 = (const float*)d_in[3];
    const float* w_hh1 = (const float*)d_in[4];
    const float* w_fc  = (const float*)d_in[5];
    float* out = (float*)d_out;

    float* h1pp = (float*)d_ws;                  // 2 x [64][1024]
    float* h2pp = h1pp + 2 * BATCH * HID;        // 2 x [64][1024]
    const int nzero = 4 * BATCH * HID;           // 262144 floats

    zero_kernel<<<(nzero + 255) / 256, 256, 0, stream>>>(h1pp, nzero);

    for (int p = 0; p <= T_STEPS; ++p) {
        step_phase<<<dim3(32, 4, 2), 1024, 0, stream>>>(
            p, x, w_ih0, w_hh0, w_ih1, w_hh1, h1pp, h2pp);
    }

    fc_kernel<<<dim3(64, 4), 256, 0, stream>>>(h2pp, w_fc, out);
}